// Round 4
// baseline (565.766 us; speedup 1.0000x reference)
//
#include <hip/hip_runtime.h>
#include <hip/hip_bf16.h>
#include <math.h>
#include <float.h>

#define B_    32
#define C_    1536
#define T_    2000
#define BOT_  128
#define EPS_  1e-4f

typedef __attribute__((ext_vector_type(8))) short short8;   // 8 bf16 bit patterns
typedef __attribute__((ext_vector_type(4))) short short4v;  // 4 bf16
typedef __attribute__((ext_vector_type(4))) float f32x4;

static __device__ __forceinline__ unsigned short f2bf(float f) {
    unsigned u = __float_as_uint(f);
    u += 0x7FFFu + ((u >> 16) & 1u);           // RTNE
    return (unsigned short)(u >> 16);
}
static __device__ __forceinline__ float bf2f(unsigned short u) {
    return __uint_as_float(((unsigned)u) << 16);
}

// ---------------------------------------------------------------------------
// K1: per-(b,c) mean and unbiased std over T (fp32 exact), AND emit bf16
// copy of x for the downstream GEMMs. float4 loads, 8B bf16x4 stores.
// ---------------------------------------------------------------------------
__global__ __launch_bounds__(256) void stats_kernel(
    const float* __restrict__ x, float* __restrict__ mean_s, float* __restrict__ std_s,
    unsigned short* __restrict__ xb16) {
    const int row = blockIdx.x;                 // b*C + c
    const float4* x4 = reinterpret_cast<const float4*>(x + (size_t)row * T_);  // 500 vec4
    unsigned short* xo = xb16 + (size_t)row * T_;
    float s1 = 0.f, s2 = 0.f;
    for (int i = threadIdx.x; i < T_ / 4; i += 256) {
        float4 v = x4[i];
        s1 += v.x + v.y + v.z + v.w;
        s2 = fmaf(v.x, v.x, fmaf(v.y, v.y, fmaf(v.z, v.z, fmaf(v.w, v.w, s2))));
        short4v pk;
        pk[0] = (short)f2bf(v.x); pk[1] = (short)f2bf(v.y);
        pk[2] = (short)f2bf(v.z); pk[3] = (short)f2bf(v.w);
        *reinterpret_cast<short4v*>(xo + 4 * i) = pk;
    }
    #pragma unroll
    for (int off = 32; off; off >>= 1) {
        s1 += __shfl_xor(s1, off);
        s2 += __shfl_xor(s2, off);
    }
    __shared__ float ls1[4], ls2[4];
    const int wave = threadIdx.x >> 6, lane = threadIdx.x & 63;
    if (lane == 0) { ls1[wave] = s1; ls2[wave] = s2; }
    __syncthreads();
    if (threadIdx.x == 0) {
        s1 = ls1[0] + ls1[1] + ls1[2] + ls1[3];
        s2 = ls2[0] + ls2[1] + ls2[2] + ls2[3];
        float mean = s1 / (float)T_;
        float var  = (s2 - s1 * mean) / (float)(T_ - 1);
        mean_s[row] = mean;
        std_s[row]  = sqrtf(fmaxf(var, EPS_));
    }
}

// ---------------------------------------------------------------------------
// K1b: convert W1[:, :C] and W2 to bf16.
// ---------------------------------------------------------------------------
__global__ __launch_bounds__(256) void cvt_kernel(
    const float* __restrict__ W1, const float* __restrict__ W2,
    unsigned short* __restrict__ W1b, unsigned short* __restrict__ W2b) {
    int idx = blockIdx.x * 256 + threadIdx.x;
    if (idx < BOT_ * C_) {
        int o = idx / C_, c = idx - o * C_;
        W1b[idx] = f2bf(W1[(size_t)o * (3 * C_) + c]);
        W2b[idx] = f2bf(W2[idx]);
    }
}

// ---------------------------------------------------------------------------
// K2: cb[b][o] = b1[o] + sum_c W1[o][C+c]*mean[b][c] + W1[o][2C+c]*std[b][c]
// 4 independent FMA chains (this kernel is on the serial critical path).
// ---------------------------------------------------------------------------
__global__ __launch_bounds__(128) void cb_kernel(
    const float* __restrict__ W1, const float* __restrict__ b1,
    const float* __restrict__ mean_s, const float* __restrict__ std_s,
    float* __restrict__ cb) {
    __shared__ float ml[C_];
    __shared__ float sl[C_];
    const int b = blockIdx.x;
    for (int c = threadIdx.x; c < C_; c += 128) {
        ml[c] = mean_s[(size_t)b * C_ + c];
        sl[c] = std_s[(size_t)b * C_ + c];
    }
    __syncthreads();
    const int o = threadIdx.x;
    const float* wm = W1 + (size_t)o * (3 * C_) + C_;
    const float* ws = wm + C_;
    float am0 = 0.f, am1 = 0.f, as0 = 0.f, as1 = 0.f;
    for (int c = 0; c < C_; c += 2) {
        am0 = fmaf(wm[c],     ml[c],     am0);
        am1 = fmaf(wm[c + 1], ml[c + 1], am1);
        as0 = fmaf(ws[c],     sl[c],     as0);
        as1 = fmaf(ws[c + 1], sl[c + 1], as1);
    }
    cb[(size_t)b * BOT_ + o] = b1[o] + (am0 + am1) + (as0 + as1);
}

// ---------------------------------------------------------------------------
// K3 (MFMA): ht[b][t][o] = bf16( relu( sum_c W1b[o][c]*xb16[b][c][t] + cb ) )
// Block tile 128o x 128t, K-chunk 64 in LDS (24 iterations). 4 waves,
// each 64o x 64t. grid = (16, B). Output t-major for K4's B-operand.
// ---------------------------------------------------------------------------
#define K3_BK  64
#define K3_PAD 72   // bf16 row stride (144 B): 16B-aligned, gcd(36dw,32)=4

__global__ __launch_bounds__(256) void gemm1_mfma(
    const unsigned short* __restrict__ xb16, const unsigned short* __restrict__ W1b,
    const float* __restrict__ cb, unsigned short* __restrict__ ht) {
    const int b   = blockIdx.y;
    const int t0  = blockIdx.x * 128;
    const int tid = threadIdx.x;
    const int lane = tid & 63;
    const int w  = tid >> 6;
    const int wr = w >> 1, wc = w & 1;       // o-half, t-half
    const int g  = lane >> 4, li = lane & 15;

    __shared__ __align__(16) unsigned short Al[128 * K3_PAD];  // [o][k]
    __shared__ __align__(16) unsigned short Bl[128 * K3_PAD];  // [t][k]

    f32x4 acc[4][4];
    #pragma unroll
    for (int mi = 0; mi < 4; ++mi)
        #pragma unroll
        for (int ni = 0; ni < 4; ++ni)
            acc[mi][ni] = (f32x4){0.f, 0.f, 0.f, 0.f};

    const unsigned short* xb = xb16 + (size_t)b * C_ * T_;

    for (int kc = 0; kc < C_; kc += K3_BK) {
        __syncthreads();
        // stage A: 128o x 64k bf16 from W1b (4 x 16B per thread)
        #pragma unroll
        for (int i = 0; i < 4; ++i) {
            int e = tid + 256 * i;            // 0..1023
            int o = e >> 3, kb = e & 7;
            short8 v = *reinterpret_cast<const short8*>(W1b + (size_t)o * C_ + kc + kb * 8);
            *reinterpret_cast<short8*>(Al + o * K3_PAD + kb * 8) = v;
        }
        // stage B: xb16 chunk 64k x 128t -> Bl[t][k] (transpose gather)
        #pragma unroll
        for (int i = 0; i < 4; ++i) {
            int e = tid + 256 * i;            // 0..1023
            int t = e & 127, kb = e >> 7;     // kb 0..7
            int tg = t0 + t;
            short8 pv;
            #pragma unroll
            for (int j = 0; j < 8; ++j)
                pv[j] = (tg < T_) ? (short)xb[(size_t)(kc + kb * 8 + j) * T_ + tg] : (short)0;
            *reinterpret_cast<short8*>(Bl + t * K3_PAD + kb * 8) = pv;
        }
        __syncthreads();
        // compute: 2 k-steps of 32, 16 MFMA each
        #pragma unroll
        for (int ks = 0; ks < 2; ++ks) {
            short8 a[4], bb[4];
            #pragma unroll
            for (int mi = 0; mi < 4; ++mi)
                a[mi] = *reinterpret_cast<const short8*>(Al + (wr * 64 + mi * 16 + li) * K3_PAD + ks * 32 + g * 8);
            #pragma unroll
            for (int ni = 0; ni < 4; ++ni)
                bb[ni] = *reinterpret_cast<const short8*>(Bl + (wc * 64 + ni * 16 + li) * K3_PAD + ks * 32 + g * 8);
            #pragma unroll
            for (int mi = 0; mi < 4; ++mi)
                #pragma unroll
                for (int ni = 0; ni < 4; ++ni)
                    acc[mi][ni] = __builtin_amdgcn_mfma_f32_16x16x32_bf16(a[mi], bb[ni], acc[mi][ni], 0, 0, 0);
        }
    }

    // epilogue: + cb, relu, bf16, store transposed ht[b][t][o]
    #pragma unroll
    for (int mi = 0; mi < 4; ++mi) {
        const int ob = wr * 64 + mi * 16 + g * 4;
        const float4 cbv = *reinterpret_cast<const float4*>(cb + (size_t)b * BOT_ + ob);
        #pragma unroll
        for (int ni = 0; ni < 4; ++ni) {
            int t = t0 + wc * 64 + ni * 16 + li;
            if (t < T_) {
                short4v pk;
                pk[0] = (short)f2bf(fmaxf(acc[mi][ni][0] + cbv.x, 0.f));
                pk[1] = (short)f2bf(fmaxf(acc[mi][ni][1] + cbv.y, 0.f));
                pk[2] = (short)f2bf(fmaxf(acc[mi][ni][2] + cbv.z, 0.f));
                pk[3] = (short)f2bf(fmaxf(acc[mi][ni][3] + cbv.w, 0.f));
                *reinterpret_cast<short4v*>(ht + ((size_t)b * T_ + t) * BOT_ + ob) = pk;
            }
        }
    }
}

// ---------------------------------------------------------------------------
// K4 (MFMA, fused): logits L[c,t] = sum_o W2b[c][o] * ht[b][t][o];
// max-free softmax over t + weighted stats (|L| <~ 3 by construction,
// b2 cancels). Per-lane-private Z/S1/S2. Block = (b, 128 c), 8 waves
// (4 c-quarters x 2 t-halves), 16 t-tiles of 128.
// ---------------------------------------------------------------------------
__global__ __launch_bounds__(512) void gemm2_mfma_fused(
    const unsigned short* __restrict__ xb16, const unsigned short* __restrict__ ht,
    const unsigned short* __restrict__ W2b, float* __restrict__ out) {
    const int b   = blockIdx.y;
    const int c0  = blockIdx.x * 128;
    const int tid = threadIdx.x;
    const int lane = tid & 63;
    const int w  = tid >> 6;          // 0..7
    const int wr = w >> 1, wc = w & 1; // wr: c-quarter (32c), wc: t-half
    const int g  = lane >> 4, li = lane & 15;

    // A frags: W2b[c][o], c = c0+wr*32+mi*16+li, o = ks*32+g*8
    short8 afr[2][4];
    #pragma unroll
    for (int mi = 0; mi < 2; ++mi)
        #pragma unroll
        for (int ks = 0; ks < 4; ++ks)
            afr[mi][ks] = *reinterpret_cast<const short8*>(
                W2b + (size_t)(c0 + wr * 32 + mi * 16 + li) * BOT_ + ks * 32 + g * 8);

    float Z_[2][4], S1_[2][4], S2_[2][4];
    #pragma unroll
    for (int mi = 0; mi < 2; ++mi)
        #pragma unroll
        for (int r = 0; r < 4; ++r) { Z_[mi][r] = 0.f; S1_[mi][r] = 0.f; S2_[mi][r] = 0.f; }

    const unsigned short* htb = ht + (size_t)b * T_ * BOT_;
    const unsigned short* xb = xb16 + ((size_t)b * C_ + c0) * T_;

    for (int it = 0; it < 16; ++it) {
        const int t0 = it * 128 + wc * 64;

        // prefetch x (bf16) for this tile
        float xv[2][4][4];
        #pragma unroll
        for (int mi = 0; mi < 2; ++mi)
            #pragma unroll
            for (int r = 0; r < 4; ++r)
                #pragma unroll
                for (int ni = 0; ni < 4; ++ni) {
                    int t = t0 + ni * 16 + li;
                    int c = wr * 32 + mi * 16 + g * 4 + r;
                    xv[mi][r][ni] = (t < T_) ? bf2f(xb[(size_t)c * T_ + t]) : 0.f;
                }

        // logits via MFMA, K = 128 in 4 steps; B-frags direct from L2/L3
        f32x4 acc[2][4];
        #pragma unroll
        for (int mi = 0; mi < 2; ++mi)
            #pragma unroll
            for (int ni = 0; ni < 4; ++ni)
                acc[mi][ni] = (f32x4){0.f, 0.f, 0.f, 0.f};
        #pragma unroll
        for (int ks = 0; ks < 4; ++ks) {
            short8 bfr[4];
            #pragma unroll
            for (int ni = 0; ni < 4; ++ni) {
                int t = t0 + ni * 16 + li;
                int tc = (t < T_) ? t : (T_ - 1);
                bfr[ni] = *reinterpret_cast<const short8*>(htb + (size_t)tc * BOT_ + ks * 32 + g * 8);
            }
            #pragma unroll
            for (int mi = 0; mi < 2; ++mi)
                #pragma unroll
                for (int ni = 0; ni < 4; ++ni)
                    acc[mi][ni] = __builtin_amdgcn_mfma_f32_16x16x32_bf16(afr[mi][ks], bfr[ni], acc[mi][ni], 0, 0, 0);
        }

        // max-free accumulation, fully per-lane
        #pragma unroll
        for (int mi = 0; mi < 2; ++mi)
            #pragma unroll
            for (int r = 0; r < 4; ++r)
                #pragma unroll
                for (int ni = 0; ni < 4; ++ni) {
                    int t = t0 + ni * 16 + li;
                    float p = __expf(acc[mi][ni][r]);
                    p = (t < T_) ? p : 0.f;
                    float xx = xv[mi][r][ni];
                    Z_[mi][r] += p;
                    S1_[mi][r] = fmaf(xx, p, S1_[mi][r]);
                    S2_[mi][r] = fmaf(xx * xx, p, S2_[mi][r]);
                }
    }

    // reduce over the 16 lanes of each group
    #pragma unroll
    for (int mi = 0; mi < 2; ++mi)
        #pragma unroll
        for (int r = 0; r < 4; ++r)
            #pragma unroll
            for (int off = 1; off < 16; off <<= 1) {
                Z_[mi][r]  += __shfl_xor(Z_[mi][r], off);
                S1_[mi][r] += __shfl_xor(S1_[mi][r], off);
                S2_[mi][r] += __shfl_xor(S2_[mi][r], off);
            }

    __shared__ float red[2][128][3];
    if (li == 0) {
        #pragma unroll
        for (int mi = 0; mi < 2; ++mi)
            #pragma unroll
            for (int r = 0; r < 4; ++r) {
                int cl = wr * 32 + mi * 16 + g * 4 + r;
                red[wc][cl][0] = Z_[mi][r];
                red[wc][cl][1] = S1_[mi][r];
                red[wc][cl][2] = S2_[mi][r];
            }
    }
    __syncthreads();
    if (tid < 128) {
        int cl = tid;
        float Z  = red[0][cl][0] + red[1][cl][0];
        float S1 = red[0][cl][1] + red[1][cl][1];
        float S2 = red[0][cl][2] + red[1][cl][2];
        float wmean = S1 / Z;
        float wsd   = sqrtf(fmaxf(S2 / Z - wmean * wmean, EPS_));
        out[(size_t)b * (2 * C_) + c0 + cl]      = wmean;
        out[(size_t)b * (2 * C_) + C_ + c0 + cl] = wsd;
    }
}

// ---------------------------------------------------------------------------
extern "C" void kernel_launch(void* const* d_in, const int* in_sizes, int n_in,
                              void* d_out, int out_size, void* d_ws, size_t ws_size,
                              hipStream_t stream) {
    const float* x  = (const float*)d_in[0];   // [B, C, T]
    const float* W1 = (const float*)d_in[1];   // [BOT, 3C]
    const float* b1 = (const float*)d_in[2];   // [BOT]
    const float* W2 = (const float*)d_in[3];   // [C, BOT]
    // b2 (d_in[4]) cancels in softmax over T
    float* out = (float*)d_out;                // [B, 2C]

    float* ws = (float*)d_ws;
    float* mean_s = ws;                                   // B*C
    float* std_s  = mean_s + (size_t)B_ * C_;             // B*C
    float* cb     = std_s  + (size_t)B_ * C_;             // B*BOT
    unsigned short* W1b = (unsigned short*)(cb + (size_t)B_ * BOT_);  // BOT*C
    unsigned short* W2b = W1b + (size_t)BOT_ * C_;                    // C*BOT
    unsigned short* ht  = W2b + (size_t)C_ * BOT_;                    // B*T*BOT
    unsigned short* xb16 = ht + (size_t)B_ * T_ * BOT_;               // B*C*T bf16

    stats_kernel<<<dim3(B_ * C_), 256, 0, stream>>>(x, mean_s, std_s, xb16);
    cvt_kernel<<<dim3((BOT_ * C_ + 255) / 256), 256, 0, stream>>>(W1, W2, W1b, W2b);
    cb_kernel<<<dim3(B_), 128, 0, stream>>>(W1, b1, mean_s, std_s, cb);
    gemm1_mfma<<<dim3(16, B_), 256, 0, stream>>>(xb16, W1b, cb, ht);
    gemm2_mfma_fused<<<dim3(C_ / 128, B_), 512, 0, stream>>>(xb16, ht, W2b, out);
}

// Round 5
// 503.970 us; speedup vs baseline: 1.1226x; 1.1226x over previous
//
#include <hip/hip_runtime.h>
#include <hip/hip_bf16.h>
#include <math.h>
#include <float.h>

#define B_    32
#define C_    1536
#define T_    2000
#define BOT_  128
#define EPS_  1e-4f

typedef __attribute__((ext_vector_type(8))) short short8;   // 8 bf16 bit patterns
typedef __attribute__((ext_vector_type(4))) short short4v;  // 4 bf16
typedef __attribute__((ext_vector_type(4))) float f32x4;

static __device__ __forceinline__ unsigned short f2bf(float f) {
    unsigned u = __float_as_uint(f);
    u += 0x7FFFu + ((u >> 16) & 1u);           // RTNE
    return (unsigned short)(u >> 16);
}
static __device__ __forceinline__ float bf2f(unsigned short u) {
    return __uint_as_float(((unsigned)u) << 16);
}

// ---------------------------------------------------------------------------
// K1: per-(b,c) mean and unbiased std over T (fp32 exact), AND emit bf16
// copy of x for the downstream GEMMs.
// ---------------------------------------------------------------------------
__global__ __launch_bounds__(256) void stats_kernel(
    const float* __restrict__ x, float* __restrict__ mean_s, float* __restrict__ std_s,
    unsigned short* __restrict__ xb16) {
    const int row = blockIdx.x;                 // b*C + c
    const float4* x4 = reinterpret_cast<const float4*>(x + (size_t)row * T_);  // 500 vec4
    unsigned short* xo = xb16 + (size_t)row * T_;
    float s1 = 0.f, s2 = 0.f;
    for (int i = threadIdx.x; i < T_ / 4; i += 256) {
        float4 v = x4[i];
        s1 += v.x + v.y + v.z + v.w;
        s2 = fmaf(v.x, v.x, fmaf(v.y, v.y, fmaf(v.z, v.z, fmaf(v.w, v.w, s2))));
        short4v pk;
        pk[0] = (short)f2bf(v.x); pk[1] = (short)f2bf(v.y);
        pk[2] = (short)f2bf(v.z); pk[3] = (short)f2bf(v.w);
        *reinterpret_cast<short4v*>(xo + 4 * i) = pk;
    }
    #pragma unroll
    for (int off = 32; off; off >>= 1) {
        s1 += __shfl_xor(s1, off);
        s2 += __shfl_xor(s2, off);
    }
    __shared__ float ls1[4], ls2[4];
    const int wave = threadIdx.x >> 6, lane = threadIdx.x & 63;
    if (lane == 0) { ls1[wave] = s1; ls2[wave] = s2; }
    __syncthreads();
    if (threadIdx.x == 0) {
        s1 = ls1[0] + ls1[1] + ls1[2] + ls1[3];
        s2 = ls2[0] + ls2[1] + ls2[2] + ls2[3];
        float mean = s1 / (float)T_;
        float var  = (s2 - s1 * mean) / (float)(T_ - 1);
        mean_s[row] = mean;
        std_s[row]  = sqrtf(fmaxf(var, EPS_));
    }
}

// ---------------------------------------------------------------------------
// K1b: convert W1[:, :C] and W2 to bf16.
// ---------------------------------------------------------------------------
__global__ __launch_bounds__(256) void cvt_kernel(
    const float* __restrict__ W1, const float* __restrict__ W2,
    unsigned short* __restrict__ W1b, unsigned short* __restrict__ W2b) {
    int idx = blockIdx.x * 256 + threadIdx.x;
    if (idx < BOT_ * C_) {
        int o = idx / C_, c = idx - o * C_;
        W1b[idx] = f2bf(W1[(size_t)o * (3 * C_) + c]);
        W2b[idx] = f2bf(W2[idx]);
    }
}

// ---------------------------------------------------------------------------
// K2: cb[b][o] = b1[o] + sum_c W1[o][C+c]*mean[b][c] + W1[o][2C+c]*std[b][c]
// ---------------------------------------------------------------------------
__global__ __launch_bounds__(128) void cb_kernel(
    const float* __restrict__ W1, const float* __restrict__ b1,
    const float* __restrict__ mean_s, const float* __restrict__ std_s,
    float* __restrict__ cb) {
    __shared__ float ml[C_];
    __shared__ float sl[C_];
    const int b = blockIdx.x;
    for (int c = threadIdx.x; c < C_; c += 128) {
        ml[c] = mean_s[(size_t)b * C_ + c];
        sl[c] = std_s[(size_t)b * C_ + c];
    }
    __syncthreads();
    const int o = threadIdx.x;
    const float* wm = W1 + (size_t)o * (3 * C_) + C_;
    const float* ws = wm + C_;
    float am0 = 0.f, am1 = 0.f, as0 = 0.f, as1 = 0.f;
    for (int c = 0; c < C_; c += 2) {
        am0 = fmaf(wm[c],     ml[c],     am0);
        am1 = fmaf(wm[c + 1], ml[c + 1], am1);
        as0 = fmaf(ws[c],     sl[c],     as0);
        as1 = fmaf(ws[c + 1], sl[c + 1], as1);
    }
    cb[(size_t)b * BOT_ + o] = b1[o] + (am0 + am1) + (as0 + as1);
}

// ---------------------------------------------------------------------------
// K3 (MFMA): ht[b][t][o] = bf16( relu( sum_c W1b[o][c]*xb16[b][c][t] + cb ) )
// Block tile 128o x 128t, K-chunk 64 in LDS. 4 waves, each 64o x 64t.
// ---------------------------------------------------------------------------
#define K3_BK  64
#define K3_PAD 72   // bf16 row stride (144 B): 16B-aligned, gcd(36dw,32)=4

__global__ __launch_bounds__(256) void gemm1_mfma(
    const unsigned short* __restrict__ xb16, const unsigned short* __restrict__ W1b,
    const float* __restrict__ cb, unsigned short* __restrict__ ht) {
    const int b   = blockIdx.y;
    const int t0  = blockIdx.x * 128;
    const int tid = threadIdx.x;
    const int lane = tid & 63;
    const int w  = tid >> 6;
    const int wr = w >> 1, wc = w & 1;       // o-half, t-half
    const int g  = lane >> 4, li = lane & 15;

    __shared__ __align__(16) unsigned short Al[128 * K3_PAD];  // [o][k]
    __shared__ __align__(16) unsigned short Bl[128 * K3_PAD];  // [t][k]

    f32x4 acc[4][4];
    #pragma unroll
    for (int mi = 0; mi < 4; ++mi)
        #pragma unroll
        for (int ni = 0; ni < 4; ++ni)
            acc[mi][ni] = (f32x4){0.f, 0.f, 0.f, 0.f};

    const unsigned short* xb = xb16 + (size_t)b * C_ * T_;

    for (int kc = 0; kc < C_; kc += K3_BK) {
        __syncthreads();
        // stage A: 128o x 64k bf16 from W1b (4 x 16B per thread)
        #pragma unroll
        for (int i = 0; i < 4; ++i) {
            int e = tid + 256 * i;            // 0..1023
            int o = e >> 3, kb = e & 7;
            short8 v = *reinterpret_cast<const short8*>(W1b + (size_t)o * C_ + kc + kb * 8);
            *reinterpret_cast<short8*>(Al + o * K3_PAD + kb * 8) = v;
        }
        // stage B: xb16 chunk 64k x 128t -> Bl[t][k] (transpose gather)
        #pragma unroll
        for (int i = 0; i < 4; ++i) {
            int e = tid + 256 * i;            // 0..1023
            int t = e & 127, kb = e >> 7;     // kb 0..7
            int tg = t0 + t;
            short8 pv;
            #pragma unroll
            for (int j = 0; j < 8; ++j)
                pv[j] = (tg < T_) ? (short)xb[(size_t)(kc + kb * 8 + j) * T_ + tg] : (short)0;
            *reinterpret_cast<short8*>(Bl + t * K3_PAD + kb * 8) = pv;
        }
        __syncthreads();
        // compute: 2 k-steps of 32, 16 MFMA each
        #pragma unroll
        for (int ks = 0; ks < 2; ++ks) {
            short8 a[4], bb[4];
            #pragma unroll
            for (int mi = 0; mi < 4; ++mi)
                a[mi] = *reinterpret_cast<const short8*>(Al + (wr * 64 + mi * 16 + li) * K3_PAD + ks * 32 + g * 8);
            #pragma unroll
            for (int ni = 0; ni < 4; ++ni)
                bb[ni] = *reinterpret_cast<const short8*>(Bl + (wc * 64 + ni * 16 + li) * K3_PAD + ks * 32 + g * 8);
            #pragma unroll
            for (int mi = 0; mi < 4; ++mi)
                #pragma unroll
                for (int ni = 0; ni < 4; ++ni)
                    acc[mi][ni] = __builtin_amdgcn_mfma_f32_16x16x32_bf16(a[mi], bb[ni], acc[mi][ni], 0, 0, 0);
        }
    }

    // epilogue: + cb, relu, bf16, store transposed ht[b][t][o]
    #pragma unroll
    for (int mi = 0; mi < 4; ++mi) {
        const int ob = wr * 64 + mi * 16 + g * 4;
        const float4 cbv = *reinterpret_cast<const float4*>(cb + (size_t)b * BOT_ + ob);
        #pragma unroll
        for (int ni = 0; ni < 4; ++ni) {
            int t = t0 + wc * 64 + ni * 16 + li;
            if (t < T_) {
                short4v pk;
                pk[0] = (short)f2bf(fmaxf(acc[mi][ni][0] + cbv.x, 0.f));
                pk[1] = (short)f2bf(fmaxf(acc[mi][ni][1] + cbv.y, 0.f));
                pk[2] = (short)f2bf(fmaxf(acc[mi][ni][2] + cbv.z, 0.f));
                pk[3] = (short)f2bf(fmaxf(acc[mi][ni][3] + cbv.w, 0.f));
                *reinterpret_cast<short4v*>(ht + ((size_t)b * T_ + t) * BOT_ + ob) = pk;
            }
        }
    }
}

// ---------------------------------------------------------------------------
// K4 (MFMA, fused): partial logit-softmax-stats over a 512-t chunk.
// Block = (b, 64 c, t-chunk of 4x128). 256 threads, 4 waves
// (wr: c-half of 32, wc: t-half of 64). x tile staged in LDS (coalesced),
// max-free exp (|L| <~ 3, b2 cancels). Emits (Z,S1,S2) partials.
// ---------------------------------------------------------------------------
#define G2_NT   4     // t-chunks per (b, c-block)
#define G2_XPAD 136   // bf16 row stride for x tile (16B-aligned, <=2-way banks)

__global__ __launch_bounds__(256) void gemm2_mfma_fused(
    const unsigned short* __restrict__ xb16, const unsigned short* __restrict__ ht,
    const unsigned short* __restrict__ W2b, float* __restrict__ part) {
    const int b   = blockIdx.z;
    const int ts  = blockIdx.y;
    const int c0  = blockIdx.x * 64;
    const int tid = threadIdx.x;
    const int lane = tid & 63;
    const int w  = tid >> 6;
    const int wr = w >> 1, wc = w & 1;
    const int g  = lane >> 4, li = lane & 15;

    __shared__ __align__(16) unsigned short Xl[64 * G2_XPAD];  // 17.4 KB

    // A frags: W2b[c][o], c = c0+wr*32+mi*16+li, o = ks*32+g*8
    short8 afr[2][4];
    #pragma unroll
    for (int mi = 0; mi < 2; ++mi)
        #pragma unroll
        for (int ks = 0; ks < 4; ++ks)
            afr[mi][ks] = *reinterpret_cast<const short8*>(
                W2b + (size_t)(c0 + wr * 32 + mi * 16 + li) * BOT_ + ks * 32 + g * 8);

    float Z_[2][4], S1_[2][4], S2_[2][4];
    #pragma unroll
    for (int mi = 0; mi < 2; ++mi)
        #pragma unroll
        for (int r = 0; r < 4; ++r) { Z_[mi][r] = 0.f; S1_[mi][r] = 0.f; S2_[mi][r] = 0.f; }

    const unsigned short* htb = ht + (size_t)b * T_ * BOT_;
    const unsigned short* xb = xb16 + ((size_t)b * C_ + c0) * T_;

    for (int it = 0; it < 4; ++it) {
        const int tt0 = (ts * 4 + it) * 128;   // tile base (128 t)

        __syncthreads();   // protect prior-iter Xl reads
        // stage x tile: 64c x 128t bf16, coalesced 16B loads
        #pragma unroll
        for (int i = 0; i < 4; ++i) {
            int e = tid + 256 * i;             // 0..1023
            int c = e >> 4, t8 = (e & 15) * 8;
            int tg = tt0 + t8;
            short8 v;
            if (tg + 8 <= T_) {
                v = *reinterpret_cast<const short8*>(xb + (size_t)c * T_ + tg);
            } else {
                #pragma unroll
                for (int j = 0; j < 8; ++j)
                    v[j] = (tg + j < T_) ? (short)xb[(size_t)c * T_ + tg + j] : (short)0;
            }
            *reinterpret_cast<short8*>(Xl + c * G2_XPAD + t8) = v;
        }
        __syncthreads();

        // logits via MFMA, K = 128 in 4 steps; B-frags direct from L2/L3
        f32x4 acc[2][4];
        #pragma unroll
        for (int mi = 0; mi < 2; ++mi)
            #pragma unroll
            for (int ni = 0; ni < 4; ++ni)
                acc[mi][ni] = (f32x4){0.f, 0.f, 0.f, 0.f};
        #pragma unroll
        for (int ks = 0; ks < 4; ++ks) {
            short8 bfr[4];
            #pragma unroll
            for (int ni = 0; ni < 4; ++ni) {
                int t = tt0 + wc * 64 + ni * 16 + li;
                int tc = (t < T_) ? t : (T_ - 1);
                bfr[ni] = *reinterpret_cast<const short8*>(htb + (size_t)tc * BOT_ + ks * 32 + g * 8);
            }
            #pragma unroll
            for (int mi = 0; mi < 2; ++mi)
                #pragma unroll
                for (int ni = 0; ni < 4; ++ni)
                    acc[mi][ni] = __builtin_amdgcn_mfma_f32_16x16x32_bf16(afr[mi][ks], bfr[ni], acc[mi][ni], 0, 0, 0);
        }

        // max-free accumulation; x from LDS
        #pragma unroll
        for (int mi = 0; mi < 2; ++mi)
            #pragma unroll
            for (int r = 0; r < 4; ++r) {
                const int cl = wr * 32 + mi * 16 + g * 4 + r;
                #pragma unroll
                for (int ni = 0; ni < 4; ++ni) {
                    int tl = wc * 64 + ni * 16 + li;
                    int t  = tt0 + tl;
                    float p = __expf(acc[mi][ni][r]);
                    p = (t < T_) ? p : 0.f;
                    float xx = bf2f(Xl[cl * G2_XPAD + tl]);
                    Z_[mi][r] += p;
                    S1_[mi][r] = fmaf(xx, p, S1_[mi][r]);
                    S2_[mi][r] = fmaf(xx * xx, p, S2_[mi][r]);
                }
            }
    }

    // reduce over the 16 lanes of each group
    #pragma unroll
    for (int mi = 0; mi < 2; ++mi)
        #pragma unroll
        for (int r = 0; r < 4; ++r)
            #pragma unroll
            for (int off = 1; off < 16; off <<= 1) {
                Z_[mi][r]  += __shfl_xor(Z_[mi][r], off);
                S1_[mi][r] += __shfl_xor(S1_[mi][r], off);
                S2_[mi][r] += __shfl_xor(S2_[mi][r], off);
            }

    __shared__ float red[2][64][3];
    if (li == 0) {
        #pragma unroll
        for (int mi = 0; mi < 2; ++mi)
            #pragma unroll
            for (int r = 0; r < 4; ++r) {
                int cl = wr * 32 + mi * 16 + g * 4 + r;
                red[wc][cl][0] = Z_[mi][r];
                red[wc][cl][1] = S1_[mi][r];
                red[wc][cl][2] = S2_[mi][r];
            }
    }
    __syncthreads();
    if (tid < 64) {
        int cl = tid;
        float Z  = red[0][cl][0] + red[1][cl][0];
        float S1 = red[0][cl][1] + red[1][cl][1];
        float S2 = red[0][cl][2] + red[1][cl][2];
        // part layout: [b][ts][q][C], q in {Z,S1,S2} -> coalesced
        float* pb = part + (((size_t)b * G2_NT + ts) * 3) * C_ + (c0 + cl);
        pb[0]        = Z;
        pb[C_]       = S1;
        pb[2 * C_]   = S2;
    }
}

// ---------------------------------------------------------------------------
// K5: fold the G2_NT t-chunk partials, finalize wmean/wsd.
// grid (C/256, B), 256 threads.
// ---------------------------------------------------------------------------
__global__ __launch_bounds__(256) void reduce_kernel(
    const float* __restrict__ part, float* __restrict__ out) {
    const int c = blockIdx.x * 256 + threadIdx.x;
    const int b = blockIdx.y;
    float Z = 0.f, S1 = 0.f, S2 = 0.f;
    #pragma unroll
    for (int ts = 0; ts < G2_NT; ++ts) {
        const float* pb = part + (((size_t)b * G2_NT + ts) * 3) * C_ + c;
        Z  += pb[0];
        S1 += pb[C_];
        S2 += pb[2 * C_];
    }
    float wmean = S1 / Z;
    float wsd   = sqrtf(fmaxf(S2 / Z - wmean * wmean, EPS_));
    out[(size_t)b * (2 * C_) + c]      = wmean;
    out[(size_t)b * (2 * C_) + C_ + c] = wsd;
}

// ---------------------------------------------------------------------------
extern "C" void kernel_launch(void* const* d_in, const int* in_sizes, int n_in,
                              void* d_out, int out_size, void* d_ws, size_t ws_size,
                              hipStream_t stream) {
    const float* x  = (const float*)d_in[0];   // [B, C, T]
    const float* W1 = (const float*)d_in[1];   // [BOT, 3C]
    const float* b1 = (const float*)d_in[2];   // [BOT]
    const float* W2 = (const float*)d_in[3];   // [C, BOT]
    // b2 (d_in[4]) cancels in softmax over T
    float* out = (float*)d_out;                // [B, 2C]

    float* ws = (float*)d_ws;
    float* mean_s = ws;                                   // B*C
    float* std_s  = mean_s + (size_t)B_ * C_;             // B*C
    float* cb     = std_s  + (size_t)B_ * C_;             // B*BOT
    float* part   = cb + (size_t)B_ * BOT_;               // B*NT*3*C
    unsigned short* W1b = (unsigned short*)(part + (size_t)B_ * G2_NT * 3 * C_);
    unsigned short* W2b = W1b + (size_t)BOT_ * C_;                    // C*BOT
    unsigned short* ht  = W2b + (size_t)C_ * BOT_;                    // B*T*BOT
    unsigned short* xb16 = ht + (size_t)B_ * T_ * BOT_;               // B*C*T bf16

    stats_kernel<<<dim3(B_ * C_), 256, 0, stream>>>(x, mean_s, std_s, xb16);
    cvt_kernel<<<dim3((BOT_ * C_ + 255) / 256), 256, 0, stream>>>(W1, W2, W1b, W2b);
    cb_kernel<<<dim3(B_), 128, 0, stream>>>(W1, b1, mean_s, std_s, cb);
    gemm1_mfma<<<dim3(16, B_), 256, 0, stream>>>(xb16, W1b, cb, ht);
    gemm2_mfma_fused<<<dim3(C_ / 64, G2_NT, B_), 256, 0, stream>>>(xb16, ht, W2b, part);
    reduce_kernel<<<dim3(C_ / 256, B_), 256, 0, stream>>>(part, out);
}

// Round 6
// 428.438 us; speedup vs baseline: 1.3205x; 1.1763x over previous
//
#include <hip/hip_runtime.h>
#include <hip/hip_bf16.h>
#include <math.h>
#include <float.h>

#define B_    32
#define C_    1536
#define T_    2000
#define BOT_  128
#define EPS_  1e-4f

#define CH    64    // c-chunk in fused kernel
#define TC    64    // t-chunk per block
#define NTS   32    // ceil(2000/64)
#define XB_PAD 72   // Xb row stride (ushort)
#define HL_PAD 136  // Hl row stride (ushort)

typedef __attribute__((ext_vector_type(8))) short short8;
typedef __attribute__((ext_vector_type(4))) short short4v;
typedef __attribute__((ext_vector_type(4))) float f32x4;

static __device__ __forceinline__ unsigned short f2bf(float f) {
    unsigned u = __float_as_uint(f);
    u += 0x7FFFu + ((u >> 16) & 1u);           // RTNE
    return (unsigned short)(u >> 16);
}

// ---------------------------------------------------------------------------
// K1: per-(b,c) mean and unbiased std over T (fp32 exact).
// ---------------------------------------------------------------------------
__global__ __launch_bounds__(256) void stats_kernel(
    const float* __restrict__ x, float* __restrict__ mean_s, float* __restrict__ std_s) {
    const int row = blockIdx.x;                 // b*C + c
    const float4* x4 = reinterpret_cast<const float4*>(x + (size_t)row * T_);  // 500 vec4
    float s1 = 0.f, s2 = 0.f;
    for (int i = threadIdx.x; i < T_ / 4; i += 256) {
        float4 v = x4[i];
        s1 += v.x + v.y + v.z + v.w;
        s2 = fmaf(v.x, v.x, fmaf(v.y, v.y, fmaf(v.z, v.z, fmaf(v.w, v.w, s2))));
    }
    #pragma unroll
    for (int off = 32; off; off >>= 1) {
        s1 += __shfl_xor(s1, off);
        s2 += __shfl_xor(s2, off);
    }
    __shared__ float ls1[4], ls2[4];
    const int wave = threadIdx.x >> 6, lane = threadIdx.x & 63;
    if (lane == 0) { ls1[wave] = s1; ls2[wave] = s2; }
    __syncthreads();
    if (threadIdx.x == 0) {
        s1 = ls1[0] + ls1[1] + ls1[2] + ls1[3];
        s2 = ls2[0] + ls2[1] + ls2[2] + ls2[3];
        float mean = s1 / (float)T_;
        float var  = (s2 - s1 * mean) / (float)(T_ - 1);
        mean_s[row] = mean;
        std_s[row]  = sqrtf(fmaxf(var, EPS_));
    }
}

// ---------------------------------------------------------------------------
// K1b: convert W1[:, :C] and W2 to bf16.
// ---------------------------------------------------------------------------
__global__ __launch_bounds__(256) void cvt_kernel(
    const float* __restrict__ W1, const float* __restrict__ W2,
    unsigned short* __restrict__ W1b, unsigned short* __restrict__ W2b) {
    int idx = blockIdx.x * 256 + threadIdx.x;
    if (idx < BOT_ * C_) {
        int o = idx / C_, c = idx - o * C_;
        W1b[idx] = f2bf(W1[(size_t)o * (3 * C_) + c]);
        W2b[idx] = f2bf(W2[idx]);
    }
}

// ---------------------------------------------------------------------------
// K2: cb[b][o] = b1[o] + sum_c W1[o][C+c]*mean[b][c] + W1[o][2C+c]*std[b][c]
// ---------------------------------------------------------------------------
__global__ __launch_bounds__(128) void cb_kernel(
    const float* __restrict__ W1, const float* __restrict__ b1,
    const float* __restrict__ mean_s, const float* __restrict__ std_s,
    float* __restrict__ cb) {
    __shared__ float ml[C_];
    __shared__ float sl[C_];
    const int b = blockIdx.x;
    for (int c = threadIdx.x; c < C_; c += 128) {
        ml[c] = mean_s[(size_t)b * C_ + c];
        sl[c] = std_s[(size_t)b * C_ + c];
    }
    __syncthreads();
    const int o = threadIdx.x;
    const float* wm = W1 + (size_t)o * (3 * C_) + C_;
    const float* ws = wm + C_;
    float am0 = 0.f, am1 = 0.f, as0 = 0.f, as1 = 0.f;
    for (int c = 0; c < C_; c += 2) {
        am0 = fmaf(wm[c],     ml[c],     am0);
        am1 = fmaf(wm[c + 1], ml[c + 1], am1);
        as0 = fmaf(ws[c],     sl[c],     as0);
        as1 = fmaf(ws[c + 1], sl[c + 1], as1);
    }
    cb[(size_t)b * BOT_ + o] = b1[o] + (am0 + am1) + (as0 + as1);
}

// ---------------------------------------------------------------------------
// K3 (fused): per (b, 64-t chunk):
//   phase 1: h[o,t] = relu(sum_c W1b[o][c] x[b,c,t] + cb[b][o]) via MFMA,
//            c staged in LDS 64x64 bf16 chunks; h kept in registers, then
//            written once to LDS (bf16, [t][o]).
//   phase 2: per 64-c chunk: L[c,t] = sum_o W2b[c][o] h[o,t] via MFMA
//            (Hl read-only, no barriers), max-free exp (|L|<~3, b2 cancels),
//            Z/S1/S2 accumulated per c and written as per-chunk partials.
// 4 waves. Grid (NTS, B). h/ht never touch HBM.
// ---------------------------------------------------------------------------
__global__ __launch_bounds__(256) void fused_main(
    const float* __restrict__ x, const unsigned short* __restrict__ W1b,
    const unsigned short* __restrict__ W2b, const float* __restrict__ cb,
    float* __restrict__ part) {
    const int b   = blockIdx.y;
    const int ts  = blockIdx.x;
    const int t0  = ts * TC;
    const int tid = threadIdx.x;
    const int lane = tid & 63;
    const int w   = tid >> 6;          // 0..3
    const int g   = lane >> 4, li = lane & 15;

    __shared__ __align__(16) unsigned short Xb[TC * XB_PAD];   // [t][c] 9.2KB
    __shared__ __align__(16) unsigned short Hl[TC * HL_PAD];   // [t][o] 17.4KB

    const float* xb = x + (size_t)b * C_ * T_;

    // ---------------- phase 1: h accumulation ----------------
    f32x4 hacc[2][4];
    #pragma unroll
    for (int mi = 0; mi < 2; ++mi)
        #pragma unroll
        for (int ni = 0; ni < 4; ++ni)
            hacc[mi][ni] = (f32x4){0.f, 0.f, 0.f, 0.f};

    for (int kc = 0; kc < C_; kc += CH) {
        __syncthreads();
        // stage x chunk 64c x 64t: float4 loads, transposed bf16 writes
        #pragma unroll
        for (int i = 0; i < 4; ++i) {
            int e  = tid + 256 * i;        // 0..1023
            int c  = e >> 4, t4 = e & 15;  // c 0..63, t4 0..15
            int tg = t0 + t4 * 4;
            const float* xp = xb + (size_t)(kc + c) * T_ + tg;
            float4 v;
            if (tg + 4 <= T_) {
                v = *reinterpret_cast<const float4*>(xp);
            } else {
                v.x = (tg     < T_) ? xp[0] : 0.f;
                v.y = (tg + 1 < T_) ? xp[1] : 0.f;
                v.z = (tg + 2 < T_) ? xp[2] : 0.f;
                v.w = (tg + 3 < T_) ? xp[3] : 0.f;
            }
            Xb[(t4 * 4 + 0) * XB_PAD + c] = f2bf(v.x);
            Xb[(t4 * 4 + 1) * XB_PAD + c] = f2bf(v.y);
            Xb[(t4 * 4 + 2) * XB_PAD + c] = f2bf(v.z);
            Xb[(t4 * 4 + 3) * XB_PAD + c] = f2bf(v.w);
        }
        __syncthreads();
        // wave w owns o-tile [w*32, w*32+32); K=64 in 2 steps
        #pragma unroll
        for (int ks = 0; ks < 2; ++ks) {
            short8 a[2], bb4[4];
            #pragma unroll
            for (int mi = 0; mi < 2; ++mi)
                a[mi] = *reinterpret_cast<const short8*>(
                    W1b + (size_t)(w * 32 + mi * 16 + li) * C_ + kc + ks * 32 + g * 8);
            #pragma unroll
            for (int ni = 0; ni < 4; ++ni)
                bb4[ni] = *reinterpret_cast<const short8*>(
                    Xb + (ni * 16 + li) * XB_PAD + ks * 32 + g * 8);
            #pragma unroll
            for (int mi = 0; mi < 2; ++mi)
                #pragma unroll
                for (int ni = 0; ni < 4; ++ni)
                    hacc[mi][ni] = __builtin_amdgcn_mfma_f32_16x16x32_bf16(a[mi], bb4[ni], hacc[mi][ni], 0, 0, 0);
        }
    }

    // epilogue: +cb, relu, bf16 -> Hl[t][o]
    __syncthreads();
    #pragma unroll
    for (int mi = 0; mi < 2; ++mi) {
        const int ob = w * 32 + mi * 16 + g * 4;
        const float4 cbv = *reinterpret_cast<const float4*>(cb + (size_t)b * BOT_ + ob);
        #pragma unroll
        for (int ni = 0; ni < 4; ++ni) {
            int t = ni * 16 + li;
            short4v pk;
            pk[0] = (short)f2bf(fmaxf(hacc[mi][ni][0] + cbv.x, 0.f));
            pk[1] = (short)f2bf(fmaxf(hacc[mi][ni][1] + cbv.y, 0.f));
            pk[2] = (short)f2bf(fmaxf(hacc[mi][ni][2] + cbv.z, 0.f));
            pk[3] = (short)f2bf(fmaxf(hacc[mi][ni][3] + cbv.w, 0.f));
            *reinterpret_cast<short4v*>(Hl + t * HL_PAD + ob) = pk;
        }
    }
    __syncthreads();

    // ---------------- phase 2: logits + softmax-stats ----------------
    float* pbase = part + (((size_t)b * NTS + ts) * 3) * C_;

    for (int cc = 0; cc < C_; cc += CH) {
        // x fp32 gathers for weighted sums (issued early; L2-warm)
        float xv[4][4];
        #pragma unroll
        for (int r = 0; r < 4; ++r) {
            const int c = cc + w * 16 + g * 4 + r;
            #pragma unroll
            for (int ni = 0; ni < 4; ++ni) {
                int t = t0 + ni * 16 + li;
                xv[r][ni] = (t < T_) ? xb[(size_t)c * T_ + t] : 0.f;
            }
        }
        // A-frags: W2b rows c = cc + w*16 + li
        short8 afr[4];
        #pragma unroll
        for (int ks = 0; ks < 4; ++ks)
            afr[ks] = *reinterpret_cast<const short8*>(
                W2b + (size_t)(cc + w * 16 + li) * BOT_ + ks * 32 + g * 8);
        // logits
        f32x4 lacc[4];
        #pragma unroll
        for (int ni = 0; ni < 4; ++ni) lacc[ni] = (f32x4){0.f, 0.f, 0.f, 0.f};
        #pragma unroll
        for (int ks = 0; ks < 4; ++ks) {
            short8 bfr[4];
            #pragma unroll
            for (int ni = 0; ni < 4; ++ni)
                bfr[ni] = *reinterpret_cast<const short8*>(
                    Hl + (ni * 16 + li) * HL_PAD + ks * 32 + g * 8);
            #pragma unroll
            for (int ni = 0; ni < 4; ++ni)
                lacc[ni] = __builtin_amdgcn_mfma_f32_16x16x32_bf16(afr[ks], bfr[ni], lacc[ni], 0, 0, 0);
        }
        // max-free exp + weighted accumulation
        float Zr[4], S1r[4], S2r[4];
        #pragma unroll
        for (int r = 0; r < 4; ++r) {
            Zr[r] = 0.f; S1r[r] = 0.f; S2r[r] = 0.f;
            #pragma unroll
            for (int ni = 0; ni < 4; ++ni) {
                int t = t0 + ni * 16 + li;
                float p = __expf(lacc[ni][r]);
                p = (t < T_) ? p : 0.f;
                float xx = xv[r][ni];
                Zr[r] += p;
                S1r[r] = fmaf(xx, p, S1r[r]);
                S2r[r] = fmaf(xx * xx, p, S2r[r]);
            }
        }
        // reduce across the 16 lanes of the group
        #pragma unroll
        for (int r = 0; r < 4; ++r)
            #pragma unroll
            for (int off = 1; off < 16; off <<= 1) {
                Zr[r]  += __shfl_xor(Zr[r], off);
                S1r[r] += __shfl_xor(S1r[r], off);
                S2r[r] += __shfl_xor(S2r[r], off);
            }
        if (li == 0) {
            #pragma unroll
            for (int r = 0; r < 4; ++r) {
                int c = cc + w * 16 + g * 4 + r;
                pbase[c]          = Zr[r];
                pbase[C_ + c]     = S1r[r];
                pbase[2 * C_ + c] = S2r[r];
            }
        }
    }
}

// ---------------------------------------------------------------------------
// K4: fold the NTS t-chunk partials, finalize wmean/wsd.
// ---------------------------------------------------------------------------
__global__ __launch_bounds__(256) void reduce_kernel(
    const float* __restrict__ part, float* __restrict__ out) {
    const int c = blockIdx.x * 256 + threadIdx.x;
    const int b = blockIdx.y;
    float Z = 0.f, S1 = 0.f, S2 = 0.f;
    for (int ts = 0; ts < NTS; ++ts) {
        const float* pb = part + (((size_t)b * NTS + ts) * 3) * C_ + c;
        Z  += pb[0];
        S1 += pb[C_];
        S2 += pb[2 * C_];
    }
    float wmean = S1 / Z;
    float wsd   = sqrtf(fmaxf(S2 / Z - wmean * wmean, EPS_));
    out[(size_t)b * (2 * C_) + c]      = wmean;
    out[(size_t)b * (2 * C_) + C_ + c] = wsd;
}

// ---------------------------------------------------------------------------
extern "C" void kernel_launch(void* const* d_in, const int* in_sizes, int n_in,
                              void* d_out, int out_size, void* d_ws, size_t ws_size,
                              hipStream_t stream) {
    const float* x  = (const float*)d_in[0];   // [B, C, T]
    const float* W1 = (const float*)d_in[1];   // [BOT, 3C]
    const float* b1 = (const float*)d_in[2];   // [BOT]
    const float* W2 = (const float*)d_in[3];   // [C, BOT]
    // b2 (d_in[4]) cancels in softmax over T
    float* out = (float*)d_out;                // [B, 2C]

    float* ws = (float*)d_ws;
    float* mean_s = ws;                                   // B*C
    float* std_s  = mean_s + (size_t)B_ * C_;             // B*C
    float* cb     = std_s  + (size_t)B_ * C_;             // B*BOT
    float* part   = cb + (size_t)B_ * BOT_;               // B*NTS*3*C (18.9MB)
    unsigned short* W1b = (unsigned short*)(part + (size_t)B_ * NTS * 3 * C_);
    unsigned short* W2b = W1b + (size_t)BOT_ * C_;        // C*BOT

    stats_kernel<<<dim3(B_ * C_), 256, 0, stream>>>(x, mean_s, std_s);
    cvt_kernel<<<dim3((BOT_ * C_ + 255) / 256), 256, 0, stream>>>(W1, W2, W1b, W2b);
    cb_kernel<<<dim3(B_), 128, 0, stream>>>(W1, b1, mean_s, std_s, cb);
    fused_main<<<dim3(NTS, B_), 256, 0, stream>>>(x, W1b, W2b, cb, part);
    reduce_kernel<<<dim3(C_ / 256, B_), 256, 0, stream>>>(part, out);
}

// Round 7
// 373.370 us; speedup vs baseline: 1.5153x; 1.1475x over previous
//
#include <hip/hip_runtime.h>
#include <hip/hip_bf16.h>
#include <math.h>
#include <float.h>

#define B_    32
#define C_    1536
#define T_    2000
#define BOT_  128
#define EPS_  1e-4f

#define CH    64    // c-chunk, phase 1
#define CH2   128   // c-chunk, phase 2
#define TC    64    // t-chunk per block
#define NTS   32    // ceil(2000/64)

typedef __attribute__((ext_vector_type(8))) short short8;
typedef __attribute__((ext_vector_type(4))) short short4v;
typedef __attribute__((ext_vector_type(4))) float f32x4;

static __device__ __forceinline__ unsigned short f2bf(float f) {
    unsigned u = __float_as_uint(f);
    u += 0x7FFFu + ((u >> 16) & 1u);           // RTNE
    return (unsigned short)(u >> 16);
}

// Swizzled LDS index helpers (ushort index). 16B slots, slot ^= (row&7).
// Xb: 64 rows (t) x 64 cols (c) bf16, row = 128 B = 8 slots.
static __device__ __forceinline__ int xb_idx(int t, int c) {
    return t * 64 + (((c >> 3) ^ (t & 7)) << 3) + (c & 7);
}
// Hl: 64 rows (t) x 128 cols (o) bf16, row = 256 B = 16 slots.
static __device__ __forceinline__ int hl_idx(int t, int o) {
    return t * 128 + (((o >> 3) ^ (t & 7)) << 3) + (o & 7);
}

// ---------------------------------------------------------------------------
// K1: per-(b,c) mean and unbiased std over T (fp32 exact).
// ---------------------------------------------------------------------------
__global__ __launch_bounds__(256) void stats_kernel(
    const float* __restrict__ x, float* __restrict__ mean_s, float* __restrict__ std_s) {
    const int row = blockIdx.x;                 // b*C + c
    const float4* x4 = reinterpret_cast<const float4*>(x + (size_t)row * T_);  // 500 vec4
    float s1 = 0.f, s2 = 0.f;
    for (int i = threadIdx.x; i < T_ / 4; i += 256) {
        float4 v = x4[i];
        s1 += v.x + v.y + v.z + v.w;
        s2 = fmaf(v.x, v.x, fmaf(v.y, v.y, fmaf(v.z, v.z, fmaf(v.w, v.w, s2))));
    }
    #pragma unroll
    for (int off = 32; off; off >>= 1) {
        s1 += __shfl_xor(s1, off);
        s2 += __shfl_xor(s2, off);
    }
    __shared__ float ls1[4], ls2[4];
    const int wave = threadIdx.x >> 6, lane = threadIdx.x & 63;
    if (lane == 0) { ls1[wave] = s1; ls2[wave] = s2; }
    __syncthreads();
    if (threadIdx.x == 0) {
        s1 = ls1[0] + ls1[1] + ls1[2] + ls1[3];
        s2 = ls2[0] + ls2[1] + ls2[2] + ls2[3];
        float mean = s1 / (float)T_;
        float var  = (s2 - s1 * mean) / (float)(T_ - 1);
        mean_s[row] = mean;
        std_s[row]  = sqrtf(fmaxf(var, EPS_));
    }
}

// ---------------------------------------------------------------------------
// K1b: convert W1[:, :C] and W2 to bf16.
// ---------------------------------------------------------------------------
__global__ __launch_bounds__(256) void cvt_kernel(
    const float* __restrict__ W1, const float* __restrict__ W2,
    unsigned short* __restrict__ W1b, unsigned short* __restrict__ W2b) {
    int idx = blockIdx.x * 256 + threadIdx.x;
    if (idx < BOT_ * C_) {
        int o = idx / C_, c = idx - o * C_;
        W1b[idx] = f2bf(W1[(size_t)o * (3 * C_) + c]);
        W2b[idx] = f2bf(W2[idx]);
    }
}

// ---------------------------------------------------------------------------
// K2: cb[b][o] = b1[o] + sum_c W1[o][C+c]*mean[b][c] + W1[o][2C+c]*std[b][c]
// ---------------------------------------------------------------------------
__global__ __launch_bounds__(128) void cb_kernel(
    const float* __restrict__ W1, const float* __restrict__ b1,
    const float* __restrict__ mean_s, const float* __restrict__ std_s,
    float* __restrict__ cb) {
    __shared__ float ml[C_];
    __shared__ float sl[C_];
    const int b = blockIdx.x;
    for (int c = threadIdx.x; c < C_; c += 128) {
        ml[c] = mean_s[(size_t)b * C_ + c];
        sl[c] = std_s[(size_t)b * C_ + c];
    }
    __syncthreads();
    const int o = threadIdx.x;
    const float* wm = W1 + (size_t)o * (3 * C_) + C_;
    const float* ws = wm + C_;
    float am0 = 0.f, am1 = 0.f, as0 = 0.f, as1 = 0.f;
    for (int c = 0; c < C_; c += 2) {
        am0 = fmaf(wm[c],     ml[c],     am0);
        am1 = fmaf(wm[c + 1], ml[c + 1], am1);
        as0 = fmaf(ws[c],     sl[c],     as0);
        as1 = fmaf(ws[c + 1], sl[c + 1], as1);
    }
    cb[(size_t)b * BOT_ + o] = b1[o] + (am0 + am1) + (as0 + as1);
}

// ---------------------------------------------------------------------------
// K3 (fused): per (b, 64-t chunk):
//  phase 1: h[o,t] = relu(W1b.x + cb) via MFMA; x staged in swizzled LDS
//           (double-buffered global loads); h -> swizzled Hl[t][o] bf16.
//  phase 2: 12 chunks of 128 c: L = W2b.h via MFMA (Hl read-only, swizzle
//           => conflict-free), max-free exp (|L|<~3, b2 cancels), per-c
//           Z/S1/S2 partials written to ws.
// 4 waves, grid (NTS, B). h never touches HBM.
// ---------------------------------------------------------------------------
__global__ __launch_bounds__(256) void fused_main(
    const float* __restrict__ x, const unsigned short* __restrict__ W1b,
    const unsigned short* __restrict__ W2b, const float* __restrict__ cb,
    float* __restrict__ part) {
    const int b   = blockIdx.y;
    const int ts  = blockIdx.x;
    const int t0  = ts * TC;
    const int tid = threadIdx.x;
    const int lane = tid & 63;
    const int w   = tid >> 6;          // 0..3
    const int g   = lane >> 4, li = lane & 15;

    __shared__ __align__(16) unsigned short Xb[64 * 64];    // swizzled, 8KB
    __shared__ __align__(16) unsigned short Hl[64 * 128];   // swizzled, 16KB

    const float* xb = x + (size_t)b * C_ * T_;

    // staging coords (fixed per thread): c_s = chunk-local c, t4_s*4 = t base
    // 4 (c, t4) pairs per thread over i.
    // ---------------- phase 1 ----------------
    f32x4 hacc[2][4];
    #pragma unroll
    for (int mi = 0; mi < 2; ++mi)
        #pragma unroll
        for (int ni = 0; ni < 4; ++ni)
            hacc[mi][ni] = (f32x4){0.f, 0.f, 0.f, 0.f};

    float4 xr[4];
    // preload chunk 0
    #pragma unroll
    for (int i = 0; i < 4; ++i) {
        int e = tid + 256 * i;
        int c = e >> 4, t4 = e & 15;
        int tg = t0 + t4 * 4;
        const float* xp = xb + (size_t)c * T_ + tg;
        if (tg + 4 <= T_) {
            xr[i] = *reinterpret_cast<const float4*>(xp);
        } else {
            xr[i].x = (tg     < T_) ? xp[0] : 0.f;
            xr[i].y = (tg + 1 < T_) ? xp[1] : 0.f;
            xr[i].z = (tg + 2 < T_) ? xp[2] : 0.f;
            xr[i].w = (tg + 3 < T_) ? xp[3] : 0.f;
        }
    }

    for (int kc = 0; kc < C_; kc += CH) {
        __syncthreads();   // prior-iter Xb reads complete
        // write staged regs -> Xb (transposed, swizzled)
        #pragma unroll
        for (int i = 0; i < 4; ++i) {
            int e = tid + 256 * i;
            int c = e >> 4, t4 = e & 15;
            Xb[xb_idx(t4 * 4 + 0, c)] = f2bf(xr[i].x);
            Xb[xb_idx(t4 * 4 + 1, c)] = f2bf(xr[i].y);
            Xb[xb_idx(t4 * 4 + 2, c)] = f2bf(xr[i].z);
            Xb[xb_idx(t4 * 4 + 3, c)] = f2bf(xr[i].w);
        }
        // issue next chunk's global loads (in flight during MFMA)
        if (kc + CH < C_) {
            #pragma unroll
            for (int i = 0; i < 4; ++i) {
                int e = tid + 256 * i;
                int c = e >> 4, t4 = e & 15;
                int tg = t0 + t4 * 4;
                const float* xp = xb + (size_t)(kc + CH + c) * T_ + tg;
                if (tg + 4 <= T_) {
                    xr[i] = *reinterpret_cast<const float4*>(xp);
                } else {
                    xr[i].x = (tg     < T_) ? xp[0] : 0.f;
                    xr[i].y = (tg + 1 < T_) ? xp[1] : 0.f;
                    xr[i].z = (tg + 2 < T_) ? xp[2] : 0.f;
                    xr[i].w = (tg + 3 < T_) ? xp[3] : 0.f;
                }
            }
        }
        __syncthreads();
        // wave w owns o-rows [w*32, w*32+32); K=64 in 2 steps of 32
        #pragma unroll
        for (int ks = 0; ks < 2; ++ks) {
            short8 a[2], bb4[4];
            #pragma unroll
            for (int mi = 0; mi < 2; ++mi)
                a[mi] = *reinterpret_cast<const short8*>(
                    W1b + (size_t)(w * 32 + mi * 16 + li) * C_ + kc + ks * 32 + g * 8);
            #pragma unroll
            for (int ni = 0; ni < 4; ++ni)
                bb4[ni] = *reinterpret_cast<const short8*>(
                    &Xb[(ni * 16 + li) * 64 + (((ks * 4 + g) ^ (li & 7)) << 3)]);
            #pragma unroll
            for (int mi = 0; mi < 2; ++mi)
                #pragma unroll
                for (int ni = 0; ni < 4; ++ni)
                    hacc[mi][ni] = __builtin_amdgcn_mfma_f32_16x16x32_bf16(a[mi], bb4[ni], hacc[mi][ni], 0, 0, 0);
        }
    }

    // epilogue: +cb, relu, bf16 -> Hl[t][o] (swizzled, 8B writes)
    __syncthreads();
    #pragma unroll
    for (int mi = 0; mi < 2; ++mi) {
        const int ob = w * 32 + mi * 16 + g * 4;
        const float4 cbv = *reinterpret_cast<const float4*>(cb + (size_t)b * BOT_ + ob);
        #pragma unroll
        for (int ni = 0; ni < 4; ++ni) {
            int t = ni * 16 + li;
            short4v pk;
            pk[0] = (short)f2bf(fmaxf(hacc[mi][ni][0] + cbv.x, 0.f));
            pk[1] = (short)f2bf(fmaxf(hacc[mi][ni][1] + cbv.y, 0.f));
            pk[2] = (short)f2bf(fmaxf(hacc[mi][ni][2] + cbv.z, 0.f));
            pk[3] = (short)f2bf(fmaxf(hacc[mi][ni][3] + cbv.w, 0.f));
            // slot = ob>>3 = w*4+mi*2+(g>>1); within-slot ushort = (g&1)*4
            *reinterpret_cast<short4v*>(
                &Hl[t * 128 + (((w * 4 + mi * 2 + (g >> 1)) ^ (t & 7)) << 3) + (g & 1) * 4]) = pk;
        }
    }
    __syncthreads();

    // ---------------- phase 2: logits + softmax-stats ----------------
    float* pbase = part + (((size_t)b * NTS + ts) * 3) * C_;

    for (int cc = 0; cc < C_; cc += CH2) {
        // fp32 x gathers for weighted sums (issued early, L2-warm)
        float xv[2][4][4];
        #pragma unroll
        for (int mi = 0; mi < 2; ++mi)
            #pragma unroll
            for (int r = 0; r < 4; ++r) {
                const int c = cc + w * 32 + mi * 16 + g * 4 + r;
                #pragma unroll
                for (int ni = 0; ni < 4; ++ni) {
                    int t = t0 + ni * 16 + li;
                    xv[mi][r][ni] = (t < T_) ? xb[(size_t)c * T_ + t] : 0.f;
                }
            }
        // A-frags: W2b rows c = cc + w*32 + mi*16 + li
        short8 afr[2][4];
        #pragma unroll
        for (int mi = 0; mi < 2; ++mi)
            #pragma unroll
            for (int ks = 0; ks < 4; ++ks)
                afr[mi][ks] = *reinterpret_cast<const short8*>(
                    W2b + (size_t)(cc + w * 32 + mi * 16 + li) * BOT_ + ks * 32 + g * 8);
        // logits
        f32x4 lacc[2][4];
        #pragma unroll
        for (int mi = 0; mi < 2; ++mi)
            #pragma unroll
            for (int ni = 0; ni < 4; ++ni)
                lacc[mi][ni] = (f32x4){0.f, 0.f, 0.f, 0.f};
        #pragma unroll
        for (int ks = 0; ks < 4; ++ks) {
            short8 bfr[4];
            #pragma unroll
            for (int ni = 0; ni < 4; ++ni) {
                int t = ni * 16 + li;
                bfr[ni] = *reinterpret_cast<const short8*>(
                    &Hl[t * 128 + (((ks * 4 + g) ^ (li & 7)) << 3)]);
            }
            #pragma unroll
            for (int mi = 0; mi < 2; ++mi)
                #pragma unroll
                for (int ni = 0; ni < 4; ++ni)
                    lacc[mi][ni] = __builtin_amdgcn_mfma_f32_16x16x32_bf16(afr[mi][ks], bfr[ni], lacc[mi][ni], 0, 0, 0);
        }
        // max-free exp + weighted accumulation, then 16-lane reduce
        #pragma unroll
        for (int mi = 0; mi < 2; ++mi) {
            float Zr[4], S1r[4], S2r[4];
            #pragma unroll
            for (int r = 0; r < 4; ++r) {
                Zr[r] = 0.f; S1r[r] = 0.f; S2r[r] = 0.f;
                #pragma unroll
                for (int ni = 0; ni < 4; ++ni) {
                    int t = t0 + ni * 16 + li;
                    float p = __expf(lacc[mi][ni][r]);
                    p = (t < T_) ? p : 0.f;
                    float xx = xv[mi][r][ni];
                    Zr[r] += p;
                    S1r[r] = fmaf(xx, p, S1r[r]);
                    S2r[r] = fmaf(xx * xx, p, S2r[r]);
                }
            }
            #pragma unroll
            for (int r = 0; r < 4; ++r)
                #pragma unroll
                for (int off = 1; off < 16; off <<= 1) {
                    Zr[r]  += __shfl_xor(Zr[r], off);
                    S1r[r] += __shfl_xor(S1r[r], off);
                    S2r[r] += __shfl_xor(S2r[r], off);
                }
            if (li == 0) {
                #pragma unroll
                for (int r = 0; r < 4; ++r) {
                    int c = cc + w * 32 + mi * 16 + g * 4 + r;
                    pbase[c]          = Zr[r];
                    pbase[C_ + c]     = S1r[r];
                    pbase[2 * C_ + c] = S2r[r];
                }
            }
        }
    }
}

// ---------------------------------------------------------------------------
// K4: fold the NTS t-chunk partials, finalize wmean/wsd.
// ---------------------------------------------------------------------------
__global__ __launch_bounds__(256) void reduce_kernel(
    const float* __restrict__ part, float* __restrict__ out) {
    const int c = blockIdx.x * 256 + threadIdx.x;
    const int b = blockIdx.y;
    float Z = 0.f, S1 = 0.f, S2 = 0.f;
    for (int ts = 0; ts < NTS; ++ts) {
        const float* pb = part + (((size_t)b * NTS + ts) * 3) * C_ + c;
        Z  += pb[0];
        S1 += pb[C_];
        S2 += pb[2 * C_];
    }
    float wmean = S1 / Z;
    float wsd   = sqrtf(fmaxf(S2 / Z - wmean * wmean, EPS_));
    out[(size_t)b * (2 * C_) + c]      = wmean;
    out[(size_t)b * (2 * C_) + C_ + c] = wsd;
}

// ---------------------------------------------------------------------------
extern "C" void kernel_launch(void* const* d_in, const int* in_sizes, int n_in,
                              void* d_out, int out_size, void* d_ws, size_t ws_size,
                              hipStream_t stream) {
    const float* x  = (const float*)d_in[0];   // [B, C, T]
    const float* W1 = (const float*)d_in[1];   // [BOT, 3C]
    const float* b1 = (const float*)d_in[2];   // [BOT]
    const float* W2 = (const float*)d_in[3];   // [C, BOT]
    // b2 (d_in[4]) cancels in softmax over T
    float* out = (float*)d_out;                // [B, 2C]

    float* ws = (float*)d_ws;
    float* mean_s = ws;                                   // B*C
    float* std_s  = mean_s + (size_t)B_ * C_;             // B*C
    float* cb     = std_s  + (size_t)B_ * C_;             // B*BOT
    float* part   = cb + (size_t)B_ * BOT_;               // B*NTS*3*C (18.9MB)
    unsigned short* W1b = (unsigned short*)(part + (size_t)B_ * NTS * 3 * C_);
    unsigned short* W2b = W1b + (size_t)BOT_ * C_;        // C*BOT

    stats_kernel<<<dim3(B_ * C_), 256, 0, stream>>>(x, mean_s, std_s);
    cvt_kernel<<<dim3((BOT_ * C_ + 255) / 256), 256, 0, stream>>>(W1, W2, W1b, W2b);
    cb_kernel<<<dim3(B_), 128, 0, stream>>>(W1, b1, mean_s, std_s, cb);
    fused_main<<<dim3(NTS, B_), 256, 0, stream>>>(x, W1b, W2b, cb, part);
    reduce_kernel<<<dim3(C_ / 256, B_), 256, 0, stream>>>(part, out);
}